// Round 1
// baseline (1000.088 us; speedup 1.0000x reference)
//
#include <hip/hip_runtime.h>
#include <math.h>

#define N_NODES 30000
#define N_EDGES 480000
#define N_EDGES_SL (N_EDGES + N_NODES)
#define DIM_IN 256
#define HIDS 64
#define F1 512   // HEADS*HID
#define OUTD 128
#define NGRAPH 512
#define NEG 0.2f

__device__ __forceinline__ float lrelu(float x) { return x < 0.f ? NEG * x : x; }
__device__ __forceinline__ float elu_(float x) { return x > 0.f ? x : expm1f(x); }

// ---------------- CSR build ----------------
__global__ void k_count(const int* __restrict__ ei, int* __restrict__ deg) {
    int i = blockIdx.x * blockDim.x + threadIdx.x;
    if (i < N_EDGES) atomicAdd(&deg[ei[N_EDGES + i]], 1);
}

__global__ __launch_bounds__(256) void k_scan(const int* __restrict__ deg,
                                              int* __restrict__ offs,
                                              int* __restrict__ cursor) {
    const int T = 256;
    const int CH = (N_NODES + T - 1) / T;  // 118
    int t = threadIdx.x;
    int lo = t * CH;
    int hi = min(lo + CH, N_NODES);
    int s = 0;
    for (int i = lo; i < hi; ++i) s += deg[i] + 1;  // +1: self-loop
    __shared__ int part[T];
    part[t] = s;
    __syncthreads();
    for (int off = 1; off < T; off <<= 1) {
        int v = (t >= off) ? part[t - off] : 0;
        __syncthreads();
        part[t] += v;
        __syncthreads();
    }
    int run = part[t] - s;  // exclusive
    for (int i = lo; i < hi; ++i) {
        offs[i] = run;
        cursor[i] = run;
        run += deg[i] + 1;
    }
    if (t == T - 1) offs[N_NODES] = part[T - 1];
}

__global__ void k_scatter(const int* __restrict__ ei, int* __restrict__ cursor,
                          int* __restrict__ csrc) {
    int i = blockIdx.x * blockDim.x + threadIdx.x;
    if (i >= N_EDGES_SL) return;
    int s, d;
    if (i < N_EDGES) { s = ei[i]; d = ei[N_EDGES + i]; }
    else { s = d = i - N_EDGES; }
    int p = atomicAdd(&cursor[d], 1);
    csrc[p] = s;
}

// ---------------- fp32 tiled GEMM: C[M,Nn] = A[M,K] @ B[K,Nn] ----------------
// BM=BN=64, BK=32, 256 threads, 4x4 per thread. Nn%64==0, K%32==0, M ragged.
__global__ __launch_bounds__(256) void k_gemm(const float* __restrict__ A,
                                              const float* __restrict__ B,
                                              float* __restrict__ C,
                                              int M, int Nn, int K) {
    __shared__ float As[32][68];  // [k][m], pad 68 keeps 16B alignment per row
    __shared__ float Bs[32][64];  // [k][n]
    int tid = threadIdx.x;
    int m0 = blockIdx.x * 64, n0 = blockIdx.y * 64;
    int ty = tid >> 4, tx = tid & 15;
    float acc[4][4];
#pragma unroll
    for (int i = 0; i < 4; ++i)
#pragma unroll
        for (int j = 0; j < 4; ++j) acc[i][j] = 0.f;

    for (int k0 = 0; k0 < K; k0 += 32) {
#pragma unroll
        for (int t = 0; t < 2; ++t) {
            int f = tid + t * 256;
            int r = f >> 3, c4 = (f & 7) << 2;
            int gr = m0 + r;
            float4 v = make_float4(0.f, 0.f, 0.f, 0.f);
            if (gr < M) v = *(const float4*)(A + (size_t)gr * K + k0 + c4);
            As[c4 + 0][r] = v.x; As[c4 + 1][r] = v.y;
            As[c4 + 2][r] = v.z; As[c4 + 3][r] = v.w;
        }
#pragma unroll
        for (int t = 0; t < 2; ++t) {
            int f = tid + t * 256;
            int r = f >> 4, c4 = (f & 15) << 2;
            *(float4*)&Bs[r][c4] = *(const float4*)(B + (size_t)(k0 + r) * Nn + n0 + c4);
        }
        __syncthreads();
#pragma unroll
        for (int k = 0; k < 32; ++k) {
            float4 a = *(const float4*)&As[k][ty << 2];
            float4 b = *(const float4*)&Bs[k][tx << 2];
            float av[4] = {a.x, a.y, a.z, a.w};
            float bv[4] = {b.x, b.y, b.z, b.w};
#pragma unroll
            for (int i = 0; i < 4; ++i)
#pragma unroll
                for (int j = 0; j < 4; ++j)
                    acc[i][j] = fmaf(av[i], bv[j], acc[i][j]);
        }
        __syncthreads();
    }
#pragma unroll
    for (int i = 0; i < 4; ++i) {
        int gr = m0 + (ty << 2) + i;
        if (gr < M) {
            float4 v = make_float4(acc[i][0], acc[i][1], acc[i][2], acc[i][3]);
            *(float4*)(C + (size_t)gr * Nn + n0 + (tx << 2)) = v;
        }
    }
}

// ---------------- per-node alpha projections, 8 heads ----------------
__global__ __launch_bounds__(256) void k_alphas8(const float* __restrict__ H,
                                                 const float* __restrict__ a_src,
                                                 const float* __restrict__ a_dst,
                                                 float* __restrict__ as_,
                                                 float* __restrict__ ad_) {
    int wid = blockIdx.x * 4 + (threadIdx.x >> 6);
    int lane = threadIdx.x & 63;
    if (wid >= N_NODES) return;
    const float4* hp = (const float4*)(H + (size_t)wid * F1 + lane * 8);
    float4 h0 = hp[0], h1 = hp[1];
    const float4* sp = (const float4*)(a_src + lane * 8);
    const float4* dp = (const float4*)(a_dst + lane * 8);
    float4 s0 = sp[0], s1 = sp[1], d0 = dp[0], d1 = dp[1];
    float ps = h0.x * s0.x + h0.y * s0.y + h0.z * s0.z + h0.w * s0.w +
               h1.x * s1.x + h1.y * s1.y + h1.z * s1.z + h1.w * s1.w;
    float pd = h0.x * d0.x + h0.y * d0.y + h0.z * d0.z + h0.w * d0.w +
               h1.x * d1.x + h1.y * d1.y + h1.z * d1.z + h1.w * d1.w;
#pragma unroll
    for (int off = 1; off < 8; off <<= 1) {
        ps += __shfl_xor(ps, off);
        pd += __shfl_xor(pd, off);
    }
    if ((lane & 7) == 0) {
        as_[wid * 8 + (lane >> 3)] = ps;
        ad_[wid * 8 + (lane >> 3)] = pd;
    }
}

// ---------------- softmax-aggregate, 8 heads x 64 ch ----------------
__global__ __launch_bounds__(256) void k_agg8(const float* __restrict__ H,
                                              const float* __restrict__ as_,
                                              const float* __restrict__ ad_,
                                              const int* __restrict__ offs,
                                              const int* __restrict__ csrc,
                                              const float* __restrict__ bias,
                                              float* __restrict__ out) {
    int dst = blockIdx.x * 4 + (threadIdx.x >> 6);
    int lane = threadIdx.x & 63;
    if (dst >= N_NODES) return;
    int beg = offs[dst], end = offs[dst + 1];

    // pass 1: online softmax stats. lane covers (edge-slot = lane>>3, head = lane&7)
    int hp1 = lane & 7;
    float adv1 = ad_[dst * 8 + hp1];
    float m = -INFINITY, s = 0.f;
    for (int i = beg + (lane >> 3); i < end; i += 8) {
        int src = csrc[i];
        float e = lrelu(as_[src * 8 + hp1] + adv1);
        if (e > m) { s = s * __expf(m - e) + 1.f; m = e; }
        else s += __expf(e - m);
    }
#pragma unroll
    for (int off = 8; off < 64; off <<= 1) {
        float mo = __shfl_xor(m, off);
        float so = __shfl_xor(s, off);
        float nm = fmaxf(m, mo);
        float sn = 0.f;
        if (m > -INFINITY) sn += s * __expf(m - nm);
        if (mo > -INFINITY) sn += so * __expf(mo - nm);
        m = nm; s = sn;
    }
    // pass 2: lane covers channels [lane*8, lane*8+8) -> head = lane>>3
    int h2 = lane >> 3;
    float m2 = __shfl(m, h2);
    float inv = 1.f / __shfl(s, h2);
    float adv2 = ad_[dst * 8 + h2];
    float4 a0 = make_float4(0.f, 0.f, 0.f, 0.f);
    float4 a1 = make_float4(0.f, 0.f, 0.f, 0.f);
    for (int i = beg; i < end; ++i) {
        int src = csrc[i];
        float e = lrelu(as_[src * 8 + h2] + adv2);
        float w = __expf(e - m2) * inv;
        const float4* hp = (const float4*)(H + (size_t)src * F1 + lane * 8);
        float4 x0 = hp[0], x1 = hp[1];
        a0.x = fmaf(w, x0.x, a0.x); a0.y = fmaf(w, x0.y, a0.y);
        a0.z = fmaf(w, x0.z, a0.z); a0.w = fmaf(w, x0.w, a0.w);
        a1.x = fmaf(w, x1.x, a1.x); a1.y = fmaf(w, x1.y, a1.y);
        a1.z = fmaf(w, x1.z, a1.z); a1.w = fmaf(w, x1.w, a1.w);
    }
    const float4* bp = (const float4*)(bias + lane * 8);
    float4 b0 = bp[0], b1 = bp[1];
    float4 o0 = make_float4(elu_(a0.x + b0.x), elu_(a0.y + b0.y),
                            elu_(a0.z + b0.z), elu_(a0.w + b0.w));
    float4 o1 = make_float4(elu_(a1.x + b1.x), elu_(a1.y + b1.y),
                            elu_(a1.z + b1.z), elu_(a1.w + b1.w));
    float* op = out + (size_t)dst * F1 + lane * 8;
    *(float4*)op = o0;
    *(float4*)(op + 4) = o1;
}

// ---------------- conv3: 1 head x 64 ch ----------------
__global__ __launch_bounds__(256) void k_alphas1(const float* __restrict__ H,
                                                 const float* __restrict__ a_src,
                                                 const float* __restrict__ a_dst,
                                                 float* __restrict__ as_,
                                                 float* __restrict__ ad_) {
    int wid = blockIdx.x * 4 + (threadIdx.x >> 6);
    int lane = threadIdx.x & 63;
    if (wid >= N_NODES) return;
    float h = H[(size_t)wid * 64 + lane];
    float ps = h * a_src[lane];
    float pd = h * a_dst[lane];
#pragma unroll
    for (int off = 1; off < 64; off <<= 1) {
        ps += __shfl_xor(ps, off);
        pd += __shfl_xor(pd, off);
    }
    if (lane == 0) { as_[wid] = ps; ad_[wid] = pd; }
}

__global__ __launch_bounds__(256) void k_agg1(const float* __restrict__ H,
                                              const float* __restrict__ as_,
                                              const float* __restrict__ ad_,
                                              const int* __restrict__ offs,
                                              const int* __restrict__ csrc,
                                              const float* __restrict__ bias,
                                              float* __restrict__ out) {
    int dst = blockIdx.x * 4 + (threadIdx.x >> 6);
    int lane = threadIdx.x & 63;
    if (dst >= N_NODES) return;
    int beg = offs[dst], end = offs[dst + 1];
    float adv = ad_[dst];
    float m = -INFINITY, s = 0.f;
    for (int i = beg + lane; i < end; i += 64) {
        float e = lrelu(as_[csrc[i]] + adv);
        if (e > m) { s = s * __expf(m - e) + 1.f; m = e; }
        else s += __expf(e - m);
    }
#pragma unroll
    for (int off = 1; off < 64; off <<= 1) {
        float mo = __shfl_xor(m, off);
        float so = __shfl_xor(s, off);
        float nm = fmaxf(m, mo);
        float sn = 0.f;
        if (m > -INFINITY) sn += s * __expf(m - nm);
        if (mo > -INFINITY) sn += so * __expf(mo - nm);
        m = nm; s = sn;
    }
    float inv = 1.f / s;
    float acc = 0.f;
    for (int i = beg; i < end; ++i) {
        int src = csrc[i];
        float w = __expf(lrelu(as_[src] + adv) - m) * inv;
        acc = fmaf(w, H[(size_t)src * 64 + lane], acc);
    }
    out[(size_t)dst * 64 + lane] = elu_(acc + bias[lane]);
}

// ---------------- pooling + fc ----------------
__global__ __launch_bounds__(256) void k_pool(const float* __restrict__ h,
                                              const int* __restrict__ batch,
                                              float* __restrict__ sums,
                                              float* __restrict__ cnt) {
    int n = blockIdx.x * 4 + (threadIdx.x >> 6);
    int lane = threadIdx.x & 63;
    if (n >= N_NODES) return;
    int g = batch[n];
    atomicAdd(&sums[g * 64 + lane], h[(size_t)n * 64 + lane]);
    if (lane == 0) atomicAdd(&cnt[g], 1.f);
}

__global__ __launch_bounds__(128) void k_fc(const float* __restrict__ sums,
                                            const float* __restrict__ cnt,
                                            const float* __restrict__ W,
                                            const float* __restrict__ b,
                                            float* __restrict__ out) {
    int g = blockIdx.x;
    int o = threadIdx.x;  // 128
    __shared__ float p[64];
    if (o < 64) p[o] = sums[g * 64 + o] / fmaxf(cnt[g], 1.f);
    __syncthreads();
    float acc = b[o];
#pragma unroll
    for (int k = 0; k < 64; ++k) acc = fmaf(p[k], W[k * 128 + o], acc);
    out[g * 128 + o] = acc;
}

extern "C" void kernel_launch(void* const* d_in, const int* in_sizes, int n_in,
                              void* d_out, int out_size, void* d_ws, size_t ws_size,
                              hipStream_t stream) {
    const float* x     = (const float*)d_in[0];
    const int*   ei    = (const int*)d_in[1];
    const int*   batch = (const int*)d_in[2];
    const float* W1    = (const float*)d_in[3];
    const float* as1   = (const float*)d_in[4];
    const float* ad1   = (const float*)d_in[5];
    const float* b1    = (const float*)d_in[6];
    const float* W2    = (const float*)d_in[7];
    const float* as2   = (const float*)d_in[8];
    const float* ad2   = (const float*)d_in[9];
    const float* b2    = (const float*)d_in[10];
    const float* W3    = (const float*)d_in[11];
    const float* as3   = (const float*)d_in[12];
    const float* ad3   = (const float*)d_in[13];
    const float* b3    = (const float*)d_in[14];
    const float* Wfc   = (const float*)d_in[15];
    const float* bfc   = (const float*)d_in[16];
    float* out = (float*)d_out;

    char* ws = (char*)d_ws;
    size_t off = 0;
    auto alloc = [&](size_t bytes) -> void* {
        void* p = ws + off;
        off += (bytes + 255) & ~(size_t)255;
        return p;
    };
    float* bufH  = (float*)alloc((size_t)N_NODES * F1 * 4);  // GEMM outputs (h)
    float* bufX  = (float*)alloc((size_t)N_NODES * F1 * 4);  // conv outputs
    float* asb   = (float*)alloc((size_t)N_NODES * 8 * 4);
    float* adb   = (float*)alloc((size_t)N_NODES * 8 * 4);
    int*   offs  = (int*)alloc((N_NODES + 1) * 4);
    int*   cursor= (int*)alloc(N_NODES * 4);
    int*   deg   = (int*)alloc(N_NODES * 4);
    int*   csrc  = (int*)alloc((size_t)N_EDGES_SL * 4);
    float* sums  = (float*)alloc(NGRAPH * 64 * 4);
    float* cnt   = (float*)alloc(NGRAPH * 4);

    hipMemsetAsync(deg, 0, N_NODES * 4, stream);
    hipMemsetAsync(sums, 0, NGRAPH * 64 * 4, stream);
    hipMemsetAsync(cnt, 0, NGRAPH * 4, stream);

    // CSR by dst (self-loops appended)
    k_count<<<(N_EDGES + 255) / 256, 256, 0, stream>>>(ei, deg);
    k_scan<<<1, 256, 0, stream>>>(deg, offs, cursor);
    k_scatter<<<(N_EDGES_SL + 255) / 256, 256, 0, stream>>>(ei, cursor, csrc);

    const int MT = (N_NODES + 63) / 64;  // 469
    // conv1
    k_gemm<<<dim3(MT, F1 / 64), 256, 0, stream>>>(x, W1, bufH, N_NODES, F1, DIM_IN);
    k_alphas8<<<7500, 256, 0, stream>>>(bufH, as1, ad1, asb, adb);
    k_agg8<<<7500, 256, 0, stream>>>(bufH, asb, adb, offs, csrc, b1, bufX);
    // conv2
    k_gemm<<<dim3(MT, F1 / 64), 256, 0, stream>>>(bufX, W2, bufH, N_NODES, F1, F1);
    k_alphas8<<<7500, 256, 0, stream>>>(bufH, as2, ad2, asb, adb);
    k_agg8<<<7500, 256, 0, stream>>>(bufH, asb, adb, offs, csrc, b2, bufX);
    // conv3 (1 head); h3 -> bufH[:,0:64], out3 -> bufX[:,0:64]
    k_gemm<<<dim3(MT, 1), 256, 0, stream>>>(bufX, W3, bufH, N_NODES, 64, F1);
    k_alphas1<<<7500, 256, 0, stream>>>(bufH, as3, ad3, asb, adb);
    k_agg1<<<7500, 256, 0, stream>>>(bufH, asb, adb, offs, csrc, b3, bufX);
    // pool + fc
    k_pool<<<7500, 256, 0, stream>>>(bufX, batch, sums, cnt);
    k_fc<<<NGRAPH, 128, 0, stream>>>(sums, cnt, Wfc, bfc, out);
}

// Round 2
// 790.127 us; speedup vs baseline: 1.2657x; 1.2657x over previous
//
#include <hip/hip_runtime.h>
#include <math.h>

#define N_NODES 30000
#define N_EDGES 480000
#define N_EDGES_SL (N_EDGES + N_NODES)
#define DIM_IN 256
#define F1 512   // HEADS*HID
#define NGRAPH 512
#define NEG 0.2f
#define MB_TILES 235  // ceil(30000/128)

typedef __attribute__((ext_vector_type(8))) short short8;
typedef __attribute__((ext_vector_type(4))) float f32x4;

__device__ __forceinline__ float lrelu(float x) { return x < 0.f ? NEG * x : x; }
__device__ __forceinline__ float elu_(float x) { return x > 0.f ? x : expm1f(x); }

// split fp32 -> bf16 hi + bf16 lo (round-to-nearest-even both)
__device__ __forceinline__ void cvt_split(float a, unsigned short& h, unsigned short& l) {
    unsigned u = __float_as_uint(a);
    unsigned hb = (u + 0x7fffu + ((u >> 16) & 1u)) >> 16;
    h = (unsigned short)hb;
    float res = a - __uint_as_float(hb << 16);
    unsigned v = __float_as_uint(res);
    l = (unsigned short)((v + 0x7fffu + ((v >> 16) & 1u)) >> 16);
}

// async global->LDS, 16B per lane; g is per-lane ptr, l is wave-uniform LDS base
__device__ __forceinline__ void glds16(const unsigned short* g, unsigned short* l) {
    __builtin_amdgcn_global_load_lds(
        (const __attribute__((address_space(1))) unsigned int*)g,
        (__attribute__((address_space(3))) unsigned int*)l, 16, 0, 0);
}

// ---------------- CSR build ----------------
__global__ void k_count(const int* __restrict__ ei, int* __restrict__ deg) {
    int i = blockIdx.x * blockDim.x + threadIdx.x;
    if (i < N_EDGES) atomicAdd(&deg[ei[N_EDGES + i]], 1);
}

__global__ __launch_bounds__(256) void k_scan(const int* __restrict__ deg,
                                              int* __restrict__ offs,
                                              int* __restrict__ cursor) {
    const int T = 256;
    const int CH = (N_NODES + T - 1) / T;
    int t = threadIdx.x;
    int lo = t * CH;
    int hi = min(lo + CH, N_NODES);
    int s = 0;
    for (int i = lo; i < hi; ++i) s += deg[i] + 1;  // +1: self-loop
    __shared__ int part[T];
    part[t] = s;
    __syncthreads();
    for (int off = 1; off < T; off <<= 1) {
        int v = (t >= off) ? part[t - off] : 0;
        __syncthreads();
        part[t] += v;
        __syncthreads();
    }
    int run = part[t] - s;
    for (int i = lo; i < hi; ++i) {
        int d = deg[i];           // read BEFORE cursor write (cursor may alias deg)
        offs[i] = run;
        cursor[i] = run;
        run += d + 1;
    }
    if (t == T - 1) offs[N_NODES] = part[T - 1];
}

__global__ void k_scatter(const int* __restrict__ ei, int* __restrict__ cursor,
                          int* __restrict__ csrc) {
    int i = blockIdx.x * blockDim.x + threadIdx.x;
    if (i >= N_EDGES_SL) return;
    int s, d;
    if (i < N_EDGES) { s = ei[i]; d = ei[N_EDGES + i]; }
    else { s = d = i - N_EDGES; }
    int p = atomicAdd(&cursor[d], 1);
    csrc[p] = s;
}

// ---------------- pack A [M,K] fp32 -> [mb][kb][128][32] bf16 hi/lo ----------------
__global__ __launch_bounds__(256) void k_packA(const float* __restrict__ A,
                                               unsigned short* __restrict__ hi,
                                               unsigned short* __restrict__ lo,
                                               int M, int K) {
    int t = blockIdx.x * 256 + threadIdx.x;
    int KB = K >> 5;
    int MB = (M + 127) >> 7;
    int total = MB * KB * 512;  // threads: one 8-elem chunk each
    if (t >= total) return;
    int k8 = t & 3;
    int ml = (t >> 2) & 127;
    int tmp = t >> 9;
    int kb = tmp % KB;
    int mb = tmp / KB;
    int m = mb * 128 + ml;
    int k0 = kb * 32 + k8 * 8;
    float v[8] = {0.f, 0.f, 0.f, 0.f, 0.f, 0.f, 0.f, 0.f};
    if (m < M) {
        float4 p0 = *(const float4*)(A + (size_t)m * K + k0);
        float4 p1 = *(const float4*)(A + (size_t)m * K + k0 + 4);
        v[0] = p0.x; v[1] = p0.y; v[2] = p0.z; v[3] = p0.w;
        v[4] = p1.x; v[5] = p1.y; v[6] = p1.z; v[7] = p1.w;
    }
    unsigned short h[8], l[8];
#pragma unroll
    for (int j = 0; j < 8; ++j) cvt_split(v[j], h[j], l[j]);
    size_t o = (size_t)t * 8;
    *(short8*)(hi + o) = *(short8*)h;
    *(short8*)(lo + o) = *(short8*)l;
}

// ---------------- pack W [K,Nn] fp32 -> [nb][kb][BN][32] bf16 hi/lo (n-major) -------
template <int BN>
__global__ __launch_bounds__(256) void k_packW(const float* __restrict__ W,
                                               unsigned short* __restrict__ hi,
                                               unsigned short* __restrict__ lo,
                                               int K, int Nn) {
    int t = blockIdx.x * 256 + threadIdx.x;
    int KB = K >> 5;
    int total = (Nn / BN) * KB * BN * 4;
    if (t >= total) return;
    constexpr int LB = (BN == 128) ? 7 : 6;
    int k8 = t & 3;
    int tmp = t >> 2;
    int nl = tmp & (BN - 1);
    int tmp2 = tmp >> LB;
    int kb = tmp2 % KB;
    int nb = tmp2 / KB;
    int n = nb * BN + nl;
    int k0 = kb * 32 + k8 * 8;
    unsigned short h[8], l[8];
#pragma unroll
    for (int j = 0; j < 8; ++j) cvt_split(W[(size_t)(k0 + j) * Nn + n], h[j], l[j]);
    size_t o = (size_t)t * 8;
    *(short8*)(hi + o) = *(short8*)h;
    *(short8*)(lo + o) = *(short8*)l;
}

// ---------------- split-bf16 MFMA GEMM ----------------
// C[M,Nn] = A @ B via 3-product bf16 split. Block tile 128 x (NF*32), BK=32,
// 4 waves as 2x2, wave tile 64 x (NF*16). All staging via global_load_lds w=16.
template <int KB, int NF>
__global__ __launch_bounds__(256) void k_gemm_mfma(const unsigned short* __restrict__ Ah,
                                                   const unsigned short* __restrict__ Al,
                                                   const unsigned short* __restrict__ Bh,
                                                   const unsigned short* __restrict__ Bl,
                                                   float* __restrict__ C,
                                                   int M, int Nn) {
    constexpr int BN = NF * 32;
    constexpr int SBW = BN / 64;  // B LDS segments per wave (2 for BN=128, 1 for BN=64)
    __shared__ unsigned short sAh[4096], sAl[4096], sBh[BN * 32], sBl[BN * 32];
    const int tid = threadIdx.x, lane = tid & 63, wave = tid >> 6;
    const int mb = blockIdx.x, nb = blockIdx.y;
    const int wm = (wave >> 1) * 64;
    const int wn = (wave & 1) * (BN / 2);
    const int fr = lane & 15, quad = lane >> 4;

    const unsigned short* pAh = Ah + (size_t)mb * KB * 4096;
    const unsigned short* pAl = Al + (size_t)mb * KB * 4096;
    const unsigned short* pBh = Bh + (size_t)nb * KB * (BN * 32);
    const unsigned short* pBl = Bl + (size_t)nb * KB * (BN * 32);

    f32x4 acc[4][NF];
#pragma unroll
    for (int i = 0; i < 4; ++i)
#pragma unroll
        for (int j = 0; j < NF; ++j) acc[i][j] = {0.f, 0.f, 0.f, 0.f};

    for (int kb = 0; kb < KB; ++kb) {
        const unsigned short* ah_g = pAh + kb * 4096;
        const unsigned short* al_g = pAl + kb * 4096;
        const unsigned short* bh_g = pBh + kb * (BN * 32);
        const unsigned short* bl_g = pBl + kb * (BN * 32);
#pragma unroll
        for (int s = 0; s < 2; ++s) {
            int sg = wave * 2 + s;
            glds16(ah_g + sg * 512 + lane * 8, &sAh[sg * 512]);
            glds16(al_g + sg * 512 + lane * 8, &sAl[sg * 512]);
        }
#pragma unroll
        for (int s = 0; s < SBW; ++s) {
            int sg = wave * SBW + s;
            glds16(bh_g + sg * 512 + lane * 8, &sBh[sg * 512]);
            glds16(bl_g + sg * 512 + lane * 8, &sBl[sg * 512]);
        }
        __syncthreads();  // drains vmcnt (global_load_lds) for all waves

        short8 af_h[4], af_l[4], bf_h[NF], bf_l[NF];
#pragma unroll
        for (int f = 0; f < 4; ++f) {
            int m = wm + f * 16 + fr;
            af_h[f] = *(const short8*)&sAh[m * 32 + quad * 8];
            af_l[f] = *(const short8*)&sAl[m * 32 + quad * 8];
        }
#pragma unroll
        for (int f = 0; f < NF; ++f) {
            int n = wn + f * 16 + fr;
            bf_h[f] = *(const short8*)&sBh[n * 32 + quad * 8];
            bf_l[f] = *(const short8*)&sBl[n * 32 + quad * 8];
        }
#pragma unroll
        for (int i = 0; i < 4; ++i)
#pragma unroll
            for (int j = 0; j < NF; ++j) {
                acc[i][j] = __builtin_amdgcn_mfma_f32_16x16x32_bf16(af_h[i], bf_h[j], acc[i][j], 0, 0, 0);
                acc[i][j] = __builtin_amdgcn_mfma_f32_16x16x32_bf16(af_h[i], bf_l[j], acc[i][j], 0, 0, 0);
                acc[i][j] = __builtin_amdgcn_mfma_f32_16x16x32_bf16(af_l[i], bf_h[j], acc[i][j], 0, 0, 0);
            }
        __syncthreads();
    }
    // epilogue: C/D layout col=lane&15, row=quad*4+reg
#pragma unroll
    for (int i = 0; i < 4; ++i) {
#pragma unroll
        for (int r = 0; r < 4; ++r) {
            int row = mb * 128 + wm + i * 16 + quad * 4 + r;
            if (row < M) {
#pragma unroll
                for (int j = 0; j < NF; ++j)
                    C[(size_t)row * Nn + nb * BN + wn + j * 16 + fr] = acc[i][j][r];
            }
        }
    }
}

// ---------------- per-node alpha projections, 8 heads ----------------
__global__ __launch_bounds__(256) void k_alphas8(const float* __restrict__ H,
                                                 const float* __restrict__ a_src,
                                                 const float* __restrict__ a_dst,
                                                 float* __restrict__ as_,
                                                 float* __restrict__ ad_) {
    int wid = blockIdx.x * 4 + (threadIdx.x >> 6);
    int lane = threadIdx.x & 63;
    if (wid >= N_NODES) return;
    const float4* hp = (const float4*)(H + (size_t)wid * F1 + lane * 8);
    float4 h0 = hp[0], h1 = hp[1];
    const float4* sp = (const float4*)(a_src + lane * 8);
    const float4* dp = (const float4*)(a_dst + lane * 8);
    float4 s0 = sp[0], s1 = sp[1], d0 = dp[0], d1 = dp[1];
    float ps = h0.x * s0.x + h0.y * s0.y + h0.z * s0.z + h0.w * s0.w +
               h1.x * s1.x + h1.y * s1.y + h1.z * s1.z + h1.w * s1.w;
    float pd = h0.x * d0.x + h0.y * d0.y + h0.z * d0.z + h0.w * d0.w +
               h1.x * d1.x + h1.y * d1.y + h1.z * d1.z + h1.w * d1.w;
#pragma unroll
    for (int off = 1; off < 8; off <<= 1) {
        ps += __shfl_xor(ps, off);
        pd += __shfl_xor(pd, off);
    }
    if ((lane & 7) == 0) {
        as_[wid * 8 + (lane >> 3)] = ps;
        ad_[wid * 8 + (lane >> 3)] = pd;
    }
}

// ---------------- softmax-aggregate (8 heads), writes packed bf16 hi/lo A-tiles ----
__global__ __launch_bounds__(256) void k_agg8(const float* __restrict__ H,
                                              const float* __restrict__ as_,
                                              const float* __restrict__ ad_,
                                              const int* __restrict__ offs,
                                              const int* __restrict__ csrc,
                                              const float* __restrict__ bias,
                                              unsigned short* __restrict__ outh,
                                              unsigned short* __restrict__ outl) {
    int dst = blockIdx.x * 4 + (threadIdx.x >> 6);
    int lane = threadIdx.x & 63;
    if (dst >= N_NODES) return;
    int beg = offs[dst], end = offs[dst + 1];

    // pass 1: online softmax stats. lane = (edge-slot = lane>>3, head = lane&7)
    int hp1 = lane & 7;
    float adv1 = ad_[dst * 8 + hp1];
    float m = -INFINITY, s = 0.f;
    for (int i = beg + (lane >> 3); i < end; i += 8) {
        int src = csrc[i];
        float e = lrelu(as_[src * 8 + hp1] + adv1);
        if (e > m) { s = s * __expf(m - e) + 1.f; m = e; }
        else s += __expf(e - m);
    }
#pragma unroll
    for (int off = 8; off < 64; off <<= 1) {
        float mo = __shfl_xor(m, off);
        float so = __shfl_xor(s, off);
        float nm = fmaxf(m, mo);
        float sn = 0.f;
        if (m > -INFINITY) sn += s * __expf(m - nm);
        if (mo > -INFINITY) sn += so * __expf(mo - nm);
        m = nm; s = sn;
    }
    // pass 2: lane covers channels [lane*8, lane*8+8) -> head = lane>>3
    int h2 = lane >> 3;
    float m2 = __shfl(m, h2);
    float inv = 1.f / __shfl(s, h2);
    float adv2 = ad_[dst * 8 + h2];
    float4 a0 = make_float4(0.f, 0.f, 0.f, 0.f);
    float4 a1 = make_float4(0.f, 0.f, 0.f, 0.f);
    for (int i = beg; i < end; ++i) {
        int src = csrc[i];
        float e = lrelu(as_[src * 8 + h2] + adv2);
        float w = __expf(e - m2) * inv;
        const float4* hp = (const float4*)(H + (size_t)src * F1 + lane * 8);
        float4 x0 = hp[0], x1 = hp[1];
        a0.x = fmaf(w, x0.x, a0.x); a0.y = fmaf(w, x0.y, a0.y);
        a0.z = fmaf(w, x0.z, a0.z); a0.w = fmaf(w, x0.w, a0.w);
        a1.x = fmaf(w, x1.x, a1.x); a1.y = fmaf(w, x1.y, a1.y);
        a1.z = fmaf(w, x1.z, a1.z); a1.w = fmaf(w, x1.w, a1.w);
    }
    const float4* bp = (const float4*)(bias + lane * 8);
    float4 b0 = bp[0], b1 = bp[1];
    float o[8];
    o[0] = elu_(a0.x + b0.x); o[1] = elu_(a0.y + b0.y);
    o[2] = elu_(a0.z + b0.z); o[3] = elu_(a0.w + b0.w);
    o[4] = elu_(a1.x + b1.x); o[5] = elu_(a1.y + b1.y);
    o[6] = elu_(a1.z + b1.z); o[7] = elu_(a1.w + b1.w);
    // packed write: [mb][kb=lane>>2][ml][kl=(lane&3)*8], KB=16 (512 ch)
    unsigned short h[8], l[8];
#pragma unroll
    for (int j = 0; j < 8; ++j) cvt_split(o[j], h[j], l[j]);
    int mb = dst >> 7, ml = dst & 127;
    size_t oo = (((size_t)(mb * 16 + (lane >> 2)) * 128 + ml) * 32 + (lane & 3) * 8);
    *(short8*)(outh + oo) = *(short8*)h;
    *(short8*)(outl + oo) = *(short8*)l;
}

// ---------------- conv3: 1 head x 64 ch ----------------
__global__ __launch_bounds__(256) void k_alphas1(const float* __restrict__ H,
                                                 const float* __restrict__ a_src,
                                                 const float* __restrict__ a_dst,
                                                 float* __restrict__ as_,
                                                 float* __restrict__ ad_) {
    int wid = blockIdx.x * 4 + (threadIdx.x >> 6);
    int lane = threadIdx.x & 63;
    if (wid >= N_NODES) return;
    float h = H[(size_t)wid * 64 + lane];
    float ps = h * a_src[lane];
    float pd = h * a_dst[lane];
#pragma unroll
    for (int off = 1; off < 64; off <<= 1) {
        ps += __shfl_xor(ps, off);
        pd += __shfl_xor(pd, off);
    }
    if (lane == 0) { as_[wid] = ps; ad_[wid] = pd; }
}

__global__ __launch_bounds__(256) void k_agg1(const float* __restrict__ H,
                                              const float* __restrict__ as_,
                                              const float* __restrict__ ad_,
                                              const int* __restrict__ offs,
                                              const int* __restrict__ csrc,
                                              const float* __restrict__ bias,
                                              float* __restrict__ out) {
    int dst = blockIdx.x * 4 + (threadIdx.x >> 6);
    int lane = threadIdx.x & 63;
    if (dst >= N_NODES) return;
    int beg = offs[dst], end = offs[dst + 1];
    float adv = ad_[dst];
    float m = -INFINITY, s = 0.f;
    for (int i = beg + lane; i < end; i += 64) {
        float e = lrelu(as_[csrc[i]] + adv);
        if (e > m) { s = s * __expf(m - e) + 1.f; m = e; }
        else s += __expf(e - m);
    }
#pragma unroll
    for (int off = 1; off < 64; off <<= 1) {
        float mo = __shfl_xor(m, off);
        float so = __shfl_xor(s, off);
        float nm = fmaxf(m, mo);
        float sn = 0.f;
        if (m > -INFINITY) sn += s * __expf(m - nm);
        if (mo > -INFINITY) sn += so * __expf(mo - nm);
        m = nm; s = sn;
    }
    float inv = 1.f / s;
    float acc = 0.f;
    for (int i = beg; i < end; ++i) {
        int src = csrc[i];
        float w = __expf(lrelu(as_[src] + adv) - m) * inv;
        acc = fmaf(w, H[(size_t)src * 64 + lane], acc);
    }
    out[(size_t)dst * 64 + lane] = elu_(acc + bias[lane]);
}

// ---------------- pooling + fc ----------------
__global__ __launch_bounds__(256) void k_pool(const float* __restrict__ h,
                                              const int* __restrict__ batch,
                                              float* __restrict__ sums,
                                              float* __restrict__ cnt) {
    int n = blockIdx.x * 4 + (threadIdx.x >> 6);
    int lane = threadIdx.x & 63;
    if (n >= N_NODES) return;
    int g = batch[n];
    atomicAdd(&sums[g * 64 + lane], h[(size_t)n * 64 + lane]);
    if (lane == 0) atomicAdd(&cnt[g], 1.f);
}

__global__ __launch_bounds__(128) void k_fc(const float* __restrict__ sums,
                                            const float* __restrict__ cnt,
                                            const float* __restrict__ W,
                                            const float* __restrict__ b,
                                            float* __restrict__ out) {
    int g = blockIdx.x;
    int o = threadIdx.x;  // 128
    __shared__ float p[64];
    if (o < 64) p[o] = sums[g * 64 + o] / fmaxf(cnt[g], 1.f);
    __syncthreads();
    float acc = b[o];
#pragma unroll
    for (int k = 0; k < 64; ++k) acc = fmaf(p[k], W[k * 128 + o], acc);
    out[g * 128 + o] = acc;
}

extern "C" void kernel_launch(void* const* d_in, const int* in_sizes, int n_in,
                              void* d_out, int out_size, void* d_ws, size_t ws_size,
                              hipStream_t stream) {
    const float* x     = (const float*)d_in[0];
    const int*   ei    = (const int*)d_in[1];
    const int*   batch = (const int*)d_in[2];
    const float* W1    = (const float*)d_in[3];
    const float* as1   = (const float*)d_in[4];
    const float* ad1   = (const float*)d_in[5];
    const float* b1    = (const float*)d_in[6];
    const float* W2    = (const float*)d_in[7];
    const float* as2   = (const float*)d_in[8];
    const float* ad2   = (const float*)d_in[9];
    const float* b2    = (const float*)d_in[10];
    const float* W3    = (const float*)d_in[11];
    const float* as3   = (const float*)d_in[12];
    const float* ad3   = (const float*)d_in[13];
    const float* b3    = (const float*)d_in[14];
    const float* Wfc   = (const float*)d_in[15];
    const float* bfc   = (const float*)d_in[16];
    float* out = (float*)d_out;

    char* ws = (char*)d_ws;
    size_t off = 0;
    auto alloc = [&](size_t bytes) -> void* {
        void* p = ws + off;
        off += (bytes + 255) & ~(size_t)255;
        return p;
    };
    // bufH: fp32 GEMM outputs (h), read by alphas + agg gather
    float* bufH = (float*)alloc((size_t)N_NODES * F1 * 4);                   // 61.44 MB
    // packed A operands (bf16 hi/lo), tile layout [mb][kb][128][32]; K<=512
    unsigned short* Ah = (unsigned short*)alloc((size_t)MB_TILES * 16 * 4096 * 2);  // 30.8 MB
    unsigned short* Al = (unsigned short*)alloc((size_t)MB_TILES * 16 * 4096 * 2);  // 30.8 MB
    // packed weights, reused per layer (max = W2: 4*16*128*32 elems)
    unsigned short* Wh = (unsigned short*)alloc((size_t)262144 * 2);         // 512 KB
    unsigned short* Wl = (unsigned short*)alloc((size_t)262144 * 2);         // 512 KB
    float* asb   = (float*)alloc((size_t)N_NODES * 8 * 4);
    float* adb   = (float*)alloc((size_t)N_NODES * 8 * 4);
    int*   offs  = (int*)alloc((N_NODES + 1) * 4);
    int*   deg   = (int*)alloc(N_NODES * 4);   // also reused as scatter cursor
    int*   csrc  = (int*)alloc((size_t)N_EDGES_SL * 4);
    float* sums  = (float*)alloc(NGRAPH * 64 * 4);
    float* cnt   = (float*)alloc(NGRAPH * 4);
    // conv3 agg output overlays Ah (Ah dead after gemm3 reads it)
    float* bufX3 = (float*)Ah;

    hipMemsetAsync(deg, 0, N_NODES * 4, stream);
    hipMemsetAsync(sums, 0, NGRAPH * 64 * 4, stream);
    hipMemsetAsync(cnt, 0, NGRAPH * 4, stream);

    // CSR by dst (self-loops appended); deg doubles as cursor
    k_count<<<(N_EDGES + 255) / 256, 256, 0, stream>>>(ei, deg);
    k_scan<<<1, 256, 0, stream>>>(deg, offs, deg);
    k_scatter<<<(N_EDGES_SL + 255) / 256, 256, 0, stream>>>(ei, deg, csrc);

    // ---- conv1: K=256 (KB=8), Nn=512 (BN=128, NF=4) ----
    k_packA<<<(MB_TILES * 8 * 512 + 255) / 256, 256, 0, stream>>>(x, Ah, Al, N_NODES, DIM_IN);
    k_packW<128><<<(4 * 8 * 128 * 4 + 255) / 256, 256, 0, stream>>>(W1, Wh, Wl, DIM_IN, F1);
    k_gemm_mfma<8, 4><<<dim3(MB_TILES, 4), 256, 0, stream>>>(Ah, Al, Wh, Wl, bufH, N_NODES, F1);
    k_alphas8<<<7500, 256, 0, stream>>>(bufH, as1, ad1, asb, adb);
    k_agg8<<<7500, 256, 0, stream>>>(bufH, asb, adb, offs, csrc, b1, Ah, Al);

    // ---- conv2: K=512 (KB=16), Nn=512 ----
    k_packW<128><<<(4 * 16 * 128 * 4 + 255) / 256, 256, 0, stream>>>(W2, Wh, Wl, F1, F1);
    k_gemm_mfma<16, 4><<<dim3(MB_TILES, 4), 256, 0, stream>>>(Ah, Al, Wh, Wl, bufH, N_NODES, F1);
    k_alphas8<<<7500, 256, 0, stream>>>(bufH, as2, ad2, asb, adb);
    k_agg8<<<7500, 256, 0, stream>>>(bufH, asb, adb, offs, csrc, b2, Ah, Al);

    // ---- conv3: K=512 (KB=16), Nn=64 (BN=64, NF=2) ----
    k_packW<64><<<(1 * 16 * 64 * 4 + 255) / 256, 256, 0, stream>>>(W3, Wh, Wl, F1, 64);
    k_gemm_mfma<16, 2><<<dim3(MB_TILES, 1), 256, 0, stream>>>(Ah, Al, Wh, Wl, bufH, N_NODES, 64);
    k_alphas1<<<7500, 256, 0, stream>>>(bufH, as3, ad3, asb, adb);
    k_agg1<<<7500, 256, 0, stream>>>(bufH, asb, adb, offs, csrc, b3, bufX3);

    // ---- pool + fc ----
    k_pool<<<7500, 256, 0, stream>>>(bufX3, batch, sums, cnt);
    k_fc<<<NGRAPH, 128, 0, stream>>>(sums, cnt, Wfc, bfc, out);
}

// Round 3
// 652.105 us; speedup vs baseline: 1.5336x; 1.2117x over previous
//
#include <hip/hip_runtime.h>
#include <hip/hip_fp16.h>
#include <math.h>

#define N_NODES 30000
#define N_EDGES 480000
#define N_EDGES_SL (N_EDGES + N_NODES)
#define DIM_IN 256
#define F1 512   // HEADS*HID
#define NGRAPH 512
#define NEG 0.2f
#define MB_TILES 235  // ceil(30000/128)

typedef __attribute__((ext_vector_type(8))) short short8;
typedef __attribute__((ext_vector_type(4))) float f32x4;

__device__ __forceinline__ float lrelu(float x) { return x < 0.f ? NEG * x : x; }
__device__ __forceinline__ float elu_(float x) { return x > 0.f ? x : expm1f(x); }

// split fp32 -> bf16 hi + bf16 lo (round-to-nearest-even both)
__device__ __forceinline__ void cvt_split(float a, unsigned short& h, unsigned short& l) {
    unsigned u = __float_as_uint(a);
    unsigned hb = (u + 0x7fffu + ((u >> 16) & 1u)) >> 16;
    h = (unsigned short)hb;
    float res = a - __uint_as_float(hb << 16);
    unsigned v = __float_as_uint(res);
    l = (unsigned short)((v + 0x7fffu + ((v >> 16) & 1u)) >> 16);
}

// async global->LDS, 16B per lane; g is per-lane ptr, l is wave-uniform LDS base
__device__ __forceinline__ void glds16(const unsigned short* g, unsigned short* l) {
    __builtin_amdgcn_global_load_lds(
        (const __attribute__((address_space(1))) unsigned int*)g,
        (__attribute__((address_space(3))) unsigned int*)l, 16, 0, 0);
}

// ---------------- CSR build ----------------
__global__ void k_count(const int* __restrict__ ei, int* __restrict__ deg) {
    int i = blockIdx.x * blockDim.x + threadIdx.x;
    if (i < N_EDGES) atomicAdd(&deg[ei[N_EDGES + i]], 1);
}

__global__ __launch_bounds__(256) void k_scan(const int* __restrict__ deg,
                                              int* __restrict__ offs,
                                              int* __restrict__ cursor) {
    const int T = 256;
    const int CH = (N_NODES + T - 1) / T;
    int t = threadIdx.x;
    int lo = t * CH;
    int hi = min(lo + CH, N_NODES);
    int s = 0;
    for (int i = lo; i < hi; ++i) s += deg[i] + 1;  // +1: self-loop
    __shared__ int part[T];
    part[t] = s;
    __syncthreads();
    for (int off = 1; off < T; off <<= 1) {
        int v = (t >= off) ? part[t - off] : 0;
        __syncthreads();
        part[t] += v;
        __syncthreads();
    }
    int run = part[t] - s;
    for (int i = lo; i < hi; ++i) {
        int d = deg[i];           // read BEFORE cursor write (cursor aliases deg)
        offs[i] = run;
        cursor[i] = run;
        run += d + 1;
    }
    if (t == T - 1) offs[N_NODES] = part[T - 1];
}

__global__ void k_scatter(const int* __restrict__ ei, int* __restrict__ cursor,
                          int* __restrict__ csrc) {
    int i = blockIdx.x * blockDim.x + threadIdx.x;
    if (i >= N_EDGES_SL) return;
    int s, d;
    if (i < N_EDGES) { s = ei[i]; d = ei[N_EDGES + i]; }
    else { s = d = i - N_EDGES; }
    int p = atomicAdd(&cursor[d], 1);
    csrc[p] = s;
}

// ---------------- pack A [M,K] fp32 -> [mb][kb][128][32] bf16 hi/lo ----------------
__global__ __launch_bounds__(256) void k_packA(const float* __restrict__ A,
                                               unsigned short* __restrict__ hi,
                                               unsigned short* __restrict__ lo,
                                               int M, int K) {
    int t = blockIdx.x * 256 + threadIdx.x;
    int KB = K >> 5;
    int MB = (M + 127) >> 7;
    int total = MB * KB * 512;
    if (t >= total) return;
    int k8 = t & 3;
    int ml = (t >> 2) & 127;
    int tmp = t >> 9;
    int kb = tmp % KB;
    int mb = tmp / KB;
    int m = mb * 128 + ml;
    int k0 = kb * 32 + k8 * 8;
    float v[8] = {0.f, 0.f, 0.f, 0.f, 0.f, 0.f, 0.f, 0.f};
    if (m < M) {
        float4 p0 = *(const float4*)(A + (size_t)m * K + k0);
        float4 p1 = *(const float4*)(A + (size_t)m * K + k0 + 4);
        v[0] = p0.x; v[1] = p0.y; v[2] = p0.z; v[3] = p0.w;
        v[4] = p1.x; v[5] = p1.y; v[6] = p1.z; v[7] = p1.w;
    }
    unsigned short h[8], l[8];
#pragma unroll
    for (int j = 0; j < 8; ++j) cvt_split(v[j], h[j], l[j]);
    size_t o = (size_t)t * 8;
    *(short8*)(hi + o) = *(short8*)h;
    *(short8*)(lo + o) = *(short8*)l;
}

// ---------------- pack W [K,Nn] fp32 -> [nb][kb][BN][32] bf16 hi/lo (n-major) -------
template <int BN>
__global__ __launch_bounds__(256) void k_packW(const float* __restrict__ W,
                                               unsigned short* __restrict__ hi,
                                               unsigned short* __restrict__ lo,
                                               int K, int Nn) {
    int t = blockIdx.x * 256 + threadIdx.x;
    int KB = K >> 5;
    int total = (Nn / BN) * KB * BN * 4;
    if (t >= total) return;
    constexpr int LB = (BN == 128) ? 7 : 6;
    int k8 = t & 3;
    int tmp = t >> 2;
    int nl = tmp & (BN - 1);
    int tmp2 = tmp >> LB;
    int kb = tmp2 % KB;
    int nb = tmp2 / KB;
    int n = nb * BN + nl;
    int k0 = kb * 32 + k8 * 8;
    unsigned short h[8], l[8];
#pragma unroll
    for (int j = 0; j < 8; ++j) cvt_split(W[(size_t)(k0 + j) * Nn + n], h[j], l[j]);
    size_t o = (size_t)t * 8;
    *(short8*)(hi + o) = *(short8*)h;
    *(short8*)(lo + o) = *(short8*)l;
}

// ---------------- split-bf16 MFMA GEMM, 8-head conv (Nn=512, BN=128, NF=4) ----------
// Fused epilogue: writes H as fp16 [M][512] + per-(row,head) alpha projections
// (each wave's 64 cols are exactly one head -> in-wave shfl reduce, no atomics).
template <int KB>
__global__ __launch_bounds__(256) void k_gemm8(const unsigned short* __restrict__ Ah,
                                               const unsigned short* __restrict__ Al,
                                               const unsigned short* __restrict__ Bh,
                                               const unsigned short* __restrict__ Bl,
                                               const float* __restrict__ a_src,
                                               const float* __restrict__ a_dst,
                                               __half* __restrict__ Hf,
                                               float* __restrict__ as_,
                                               float* __restrict__ ad_,
                                               int M) {
    __shared__ unsigned short sAh[4096], sAl[4096], sBh[4096], sBl[4096];
    const int tid = threadIdx.x, lane = tid & 63, wave = tid >> 6;
    const int mb = blockIdx.x, nb = blockIdx.y;
    const int wm = (wave >> 1) * 64;
    const int wn = (wave & 1) * 64;
    const int fr = lane & 15, quad = lane >> 4;

    const unsigned short* pAh = Ah + (size_t)mb * KB * 4096;
    const unsigned short* pAl = Al + (size_t)mb * KB * 4096;
    const unsigned short* pBh = Bh + (size_t)nb * KB * 4096;
    const unsigned short* pBl = Bl + (size_t)nb * KB * 4096;

    f32x4 acc[4][4];
#pragma unroll
    for (int i = 0; i < 4; ++i)
#pragma unroll
        for (int j = 0; j < 4; ++j) acc[i][j] = {0.f, 0.f, 0.f, 0.f};

    for (int kb = 0; kb < KB; ++kb) {
        const unsigned short* ah_g = pAh + kb * 4096;
        const unsigned short* al_g = pAl + kb * 4096;
        const unsigned short* bh_g = pBh + kb * 4096;
        const unsigned short* bl_g = pBl + kb * 4096;
#pragma unroll
        for (int s = 0; s < 2; ++s) {
            int sg = wave * 2 + s;
            glds16(ah_g + sg * 512 + lane * 8, &sAh[sg * 512]);
            glds16(al_g + sg * 512 + lane * 8, &sAl[sg * 512]);
            glds16(bh_g + sg * 512 + lane * 8, &sBh[sg * 512]);
            glds16(bl_g + sg * 512 + lane * 8, &sBl[sg * 512]);
        }
        __syncthreads();

        short8 af_h[4], af_l[4], bf_h[4], bf_l[4];
#pragma unroll
        for (int f = 0; f < 4; ++f) {
            int m = wm + f * 16 + fr;
            af_h[f] = *(const short8*)&sAh[m * 32 + quad * 8];
            af_l[f] = *(const short8*)&sAl[m * 32 + quad * 8];
            int n = wn + f * 16 + fr;
            bf_h[f] = *(const short8*)&sBh[n * 32 + quad * 8];
            bf_l[f] = *(const short8*)&sBl[n * 32 + quad * 8];
        }
#pragma unroll
        for (int i = 0; i < 4; ++i)
#pragma unroll
            for (int j = 0; j < 4; ++j) {
                acc[i][j] = __builtin_amdgcn_mfma_f32_16x16x32_bf16(af_h[i], bf_h[j], acc[i][j], 0, 0, 0);
                acc[i][j] = __builtin_amdgcn_mfma_f32_16x16x32_bf16(af_h[i], bf_l[j], acc[i][j], 0, 0, 0);
                acc[i][j] = __builtin_amdgcn_mfma_f32_16x16x32_bf16(af_l[i], bf_h[j], acc[i][j], 0, 0, 0);
            }
        __syncthreads();
    }
    // epilogue; C/D layout: col=lane&15, row=quad*4+reg
    const int head = (nb * 128 + wn) >> 6;  // wave's 64 cols = one head
    float avs[4], avd[4];
#pragma unroll
    for (int j = 0; j < 4; ++j) {
        avs[j] = a_src[head * 64 + j * 16 + fr];
        avd[j] = a_dst[head * 64 + j * 16 + fr];
    }
#pragma unroll
    for (int i = 0; i < 4; ++i) {
#pragma unroll
        for (int r = 0; r < 4; ++r) {
            int row = mb * 128 + wm + i * 16 + quad * 4 + r;
            bool ok = row < M;
            float vs = 0.f, vd = 0.f;
#pragma unroll
            for (int j = 0; j < 4; ++j) {
                float c = acc[i][j][r];
                vs = fmaf(c, avs[j], vs);
                vd = fmaf(c, avd[j], vd);
                if (ok) Hf[(size_t)row * F1 + nb * 128 + wn + j * 16 + fr] = __float2half(c);
            }
#pragma unroll
            for (int off = 1; off < 16; off <<= 1) {
                vs += __shfl_xor(vs, off);
                vd += __shfl_xor(vd, off);
            }
            if (ok && fr == 0) {
                as_[row * 8 + head] = vs;
                ad_[row * 8 + head] = vd;
            }
        }
    }
}

// ---------------- split-bf16 MFMA GEMM, plain fp32 out (conv3: Nn=64) ----------
template <int KB, int NF>
__global__ __launch_bounds__(256) void k_gemm_mfma(const unsigned short* __restrict__ Ah,
                                                   const unsigned short* __restrict__ Al,
                                                   const unsigned short* __restrict__ Bh,
                                                   const unsigned short* __restrict__ Bl,
                                                   float* __restrict__ C,
                                                   int M, int Nn) {
    constexpr int BN = NF * 32;
    constexpr int SBW = BN / 64;
    __shared__ unsigned short sAh[4096], sAl[4096], sBh[BN * 32], sBl[BN * 32];
    const int tid = threadIdx.x, lane = tid & 63, wave = tid >> 6;
    const int mb = blockIdx.x, nb = blockIdx.y;
    const int wm = (wave >> 1) * 64;
    const int wn = (wave & 1) * (BN / 2);
    const int fr = lane & 15, quad = lane >> 4;

    const unsigned short* pAh = Ah + (size_t)mb * KB * 4096;
    const unsigned short* pAl = Al + (size_t)mb * KB * 4096;
    const unsigned short* pBh = Bh + (size_t)nb * KB * (BN * 32);
    const unsigned short* pBl = Bl + (size_t)nb * KB * (BN * 32);

    f32x4 acc[4][NF];
#pragma unroll
    for (int i = 0; i < 4; ++i)
#pragma unroll
        for (int j = 0; j < NF; ++j) acc[i][j] = {0.f, 0.f, 0.f, 0.f};

    for (int kb = 0; kb < KB; ++kb) {
        const unsigned short* ah_g = pAh + kb * 4096;
        const unsigned short* al_g = pAl + kb * 4096;
        const unsigned short* bh_g = pBh + kb * (BN * 32);
        const unsigned short* bl_g = pBl + kb * (BN * 32);
#pragma unroll
        for (int s = 0; s < 2; ++s) {
            int sg = wave * 2 + s;
            glds16(ah_g + sg * 512 + lane * 8, &sAh[sg * 512]);
            glds16(al_g + sg * 512 + lane * 8, &sAl[sg * 512]);
        }
#pragma unroll
        for (int s = 0; s < SBW; ++s) {
            int sg = wave * SBW + s;
            glds16(bh_g + sg * 512 + lane * 8, &sBh[sg * 512]);
            glds16(bl_g + sg * 512 + lane * 8, &sBl[sg * 512]);
        }
        __syncthreads();

        short8 af_h[4], af_l[4], bf_h[NF], bf_l[NF];
#pragma unroll
        for (int f = 0; f < 4; ++f) {
            int m = wm + f * 16 + fr;
            af_h[f] = *(const short8*)&sAh[m * 32 + quad * 8];
            af_l[f] = *(const short8*)&sAl[m * 32 + quad * 8];
        }
#pragma unroll
        for (int f = 0; f < NF; ++f) {
            int n = wn + f * 16 + fr;
            bf_h[f] = *(const short8*)&sBh[n * 32 + quad * 8];
            bf_l[f] = *(const short8*)&sBl[n * 32 + quad * 8];
        }
#pragma unroll
        for (int i = 0; i < 4; ++i)
#pragma unroll
            for (int j = 0; j < NF; ++j) {
                acc[i][j] = __builtin_amdgcn_mfma_f32_16x16x32_bf16(af_h[i], bf_h[j], acc[i][j], 0, 0, 0);
                acc[i][j] = __builtin_amdgcn_mfma_f32_16x16x32_bf16(af_h[i], bf_l[j], acc[i][j], 0, 0, 0);
                acc[i][j] = __builtin_amdgcn_mfma_f32_16x16x32_bf16(af_l[i], bf_h[j], acc[i][j], 0, 0, 0);
            }
        __syncthreads();
    }
#pragma unroll
    for (int i = 0; i < 4; ++i) {
#pragma unroll
        for (int r = 0; r < 4; ++r) {
            int row = mb * 128 + wm + i * 16 + quad * 4 + r;
            if (row < M) {
#pragma unroll
                for (int j = 0; j < NF; ++j)
                    C[(size_t)row * Nn + nb * BN + wn + j * 16 + fr] = acc[i][j][r];
            }
        }
    }
}

// ---------------- softmax-aggregate (8 heads), fp16 gather, packed bf16 out --------
__global__ __launch_bounds__(256) void k_agg8(const __half* __restrict__ Hf,
                                              const float* __restrict__ as_,
                                              const float* __restrict__ ad_,
                                              const int* __restrict__ offs,
                                              const int* __restrict__ csrc,
                                              const float* __restrict__ bias,
                                              unsigned short* __restrict__ outh,
                                              unsigned short* __restrict__ outl) {
    int dst = blockIdx.x * 4 + (threadIdx.x >> 6);
    int lane = threadIdx.x & 63;
    if (dst >= N_NODES) return;
    int beg = offs[dst], end = offs[dst + 1];

    // pass 1: online softmax stats. lane = (edge-slot = lane>>3, head = lane&7)
    int hp1 = lane & 7;
    float adv1 = ad_[dst * 8 + hp1];
    float m = -INFINITY, s = 0.f;
    for (int i = beg + (lane >> 3); i < end; i += 8) {
        int src = csrc[i];
        float e = lrelu(as_[src * 8 + hp1] + adv1);
        if (e > m) { s = s * __expf(m - e) + 1.f; m = e; }
        else s += __expf(e - m);
    }
#pragma unroll
    for (int off = 8; off < 64; off <<= 1) {
        float mo = __shfl_xor(m, off);
        float so = __shfl_xor(s, off);
        float nm = fmaxf(m, mo);
        float sn = 0.f;
        if (m > -INFINITY) sn += s * __expf(m - nm);
        if (mo > -INFINITY) sn += so * __expf(mo - nm);
        m = nm; s = sn;
    }
    // pass 2: lane covers channels [lane*8, lane*8+8) -> head = lane>>3
    int h2 = lane >> 3;
    float m2 = __shfl(m, h2);
    float inv = 1.f / __shfl(s, h2);
    float adv2 = ad_[dst * 8 + h2];
    float a[8] = {0.f, 0.f, 0.f, 0.f, 0.f, 0.f, 0.f, 0.f};
    for (int i = beg; i < end; ++i) {
        int src = csrc[i];
        float e = lrelu(as_[src * 8 + h2] + adv2);
        float w = __expf(e - m2) * inv;
        uint4 u = *(const uint4*)(Hf + (size_t)src * F1 + lane * 8);
        float2 f0 = __half22float2(*(const __half2*)&u.x);
        float2 f1 = __half22float2(*(const __half2*)&u.y);
        float2 f2 = __half22float2(*(const __half2*)&u.z);
        float2 f3 = __half22float2(*(const __half2*)&u.w);
        a[0] = fmaf(w, f0.x, a[0]); a[1] = fmaf(w, f0.y, a[1]);
        a[2] = fmaf(w, f1.x, a[2]); a[3] = fmaf(w, f1.y, a[3]);
        a[4] = fmaf(w, f2.x, a[4]); a[5] = fmaf(w, f2.y, a[5]);
        a[6] = fmaf(w, f3.x, a[6]); a[7] = fmaf(w, f3.y, a[7]);
    }
    const float4* bp = (const float4*)(bias + lane * 8);
    float4 b0 = bp[0], b1 = bp[1];
    float o[8];
    o[0] = elu_(a[0] + b0.x); o[1] = elu_(a[1] + b0.y);
    o[2] = elu_(a[2] + b0.z); o[3] = elu_(a[3] + b0.w);
    o[4] = elu_(a[4] + b1.x); o[5] = elu_(a[5] + b1.y);
    o[6] = elu_(a[6] + b1.z); o[7] = elu_(a[7] + b1.w);
    // packed write: [mb][kb=lane>>2][ml][kl=(lane&3)*8], KB=16 (512 ch)
    unsigned short h[8], l[8];
#pragma unroll
    for (int j = 0; j < 8; ++j) cvt_split(o[j], h[j], l[j]);
    int mb = dst >> 7, ml = dst & 127;
    size_t oo = (((size_t)(mb * 16 + (lane >> 2)) * 128 + ml) * 32 + (lane & 3) * 8);
    *(short8*)(outh + oo) = *(short8*)h;
    *(short8*)(outl + oo) = *(short8*)l;
}

// ---------------- conv3: 1 head x 64 ch ----------------
__global__ __launch_bounds__(256) void k_alphas1(const float* __restrict__ H,
                                                 const float* __restrict__ a_src,
                                                 const float* __restrict__ a_dst,
                                                 float* __restrict__ as_,
                                                 float* __restrict__ ad_) {
    int wid = blockIdx.x * 4 + (threadIdx.x >> 6);
    int lane = threadIdx.x & 63;
    if (wid >= N_NODES) return;
    float h = H[(size_t)wid * 64 + lane];
    float ps = h * a_src[lane];
    float pd = h * a_dst[lane];
#pragma unroll
    for (int off = 1; off < 64; off <<= 1) {
        ps += __shfl_xor(ps, off);
        pd += __shfl_xor(pd, off);
    }
    if (lane == 0) { as_[wid] = ps; ad_[wid] = pd; }
}

__global__ __launch_bounds__(256) void k_agg1(const float* __restrict__ H,
                                              const float* __restrict__ as_,
                                              const float* __restrict__ ad_,
                                              const int* __restrict__ offs,
                                              const int* __restrict__ csrc,
                                              const float* __restrict__ bias,
                                              float* __restrict__ out) {
    int dst = blockIdx.x * 4 + (threadIdx.x >> 6);
    int lane = threadIdx.x & 63;
    if (dst >= N_NODES) return;
    int beg = offs[dst], end = offs[dst + 1];
    float adv = ad_[dst];
    float m = -INFINITY, s = 0.f;
    for (int i = beg + lane; i < end; i += 64) {
        float e = lrelu(as_[csrc[i]] + adv);
        if (e > m) { s = s * __expf(m - e) + 1.f; m = e; }
        else s += __expf(e - m);
    }
#pragma unroll
    for (int off = 1; off < 64; off <<= 1) {
        float mo = __shfl_xor(m, off);
        float so = __shfl_xor(s, off);
        float nm = fmaxf(m, mo);
        float sn = 0.f;
        if (m > -INFINITY) sn += s * __expf(m - nm);
        if (mo > -INFINITY) sn += so * __expf(mo - nm);
        m = nm; s = sn;
    }
    float inv = 1.f / s;
    float acc = 0.f;
    for (int i = beg; i < end; ++i) {
        int src = csrc[i];
        float w = __expf(lrelu(as_[src] + adv) - m) * inv;
        acc = fmaf(w, H[(size_t)src * 64 + lane], acc);
    }
    out[(size_t)dst * 64 + lane] = elu_(acc + bias[lane]);
}

// ---------------- pooling + fc ----------------
__global__ __launch_bounds__(256) void k_pool(const float* __restrict__ h,
                                              const int* __restrict__ batch,
                                              float* __restrict__ sums,
                                              float* __restrict__ cnt) {
    int n = blockIdx.x * 4 + (threadIdx.x >> 6);
    int lane = threadIdx.x & 63;
    if (n >= N_NODES) return;
    int g = batch[n];
    atomicAdd(&sums[g * 64 + lane], h[(size_t)n * 64 + lane]);
    if (lane == 0) atomicAdd(&cnt[g], 1.f);
}

__global__ __launch_bounds__(128) void k_fc(const float* __restrict__ sums,
                                            const float* __restrict__ cnt,
                                            const float* __restrict__ W,
                                            const float* __restrict__ b,
                                            float* __restrict__ out) {
    int g = blockIdx.x;
    int o = threadIdx.x;  // 128
    __shared__ float p[64];
    if (o < 64) p[o] = sums[g * 64 + o] / fmaxf(cnt[g], 1.f);
    __syncthreads();
    float acc = b[o];
#pragma unroll
    for (int k = 0; k < 64; ++k) acc = fmaf(p[k], W[k * 128 + o], acc);
    out[g * 128 + o] = acc;
}

extern "C" void kernel_launch(void* const* d_in, const int* in_sizes, int n_in,
                              void* d_out, int out_size, void* d_ws, size_t ws_size,
                              hipStream_t stream) {
    const float* x     = (const float*)d_in[0];
    const int*   ei    = (const int*)d_in[1];
    const int*   batch = (const int*)d_in[2];
    const float* W1    = (const float*)d_in[3];
    const float* as1   = (const float*)d_in[4];
    const float* ad1   = (const float*)d_in[5];
    const float* b1    = (const float*)d_in[6];
    const float* W2    = (const float*)d_in[7];
    const float* as2   = (const float*)d_in[8];
    const float* ad2   = (const float*)d_in[9];
    const float* b2    = (const float*)d_in[10];
    const float* W3    = (const float*)d_in[11];
    const float* as3   = (const float*)d_in[12];
    const float* ad3   = (const float*)d_in[13];
    const float* b3    = (const float*)d_in[14];
    const float* Wfc   = (const float*)d_in[15];
    const float* bfc   = (const float*)d_in[16];
    float* out = (float*)d_out;

    char* ws = (char*)d_ws;
    size_t off = 0;
    auto alloc = [&](size_t bytes) -> void* {
        void* p = ws + off;
        off += (bytes + 255) & ~(size_t)255;
        return p;
    };
    // fp16 H for conv1/conv2 (fits aggregate L2: 30.7 MB)
    __half* Hf = (__half*)alloc((size_t)N_NODES * F1 * 2);
    // fp32 H for conv3 (small)
    float* bufH3 = (float*)alloc((size_t)N_NODES * 64 * 4);
    // packed A operands (bf16 hi/lo), tile layout [mb][kb][128][32]
    unsigned short* Ah = (unsigned short*)alloc((size_t)MB_TILES * 16 * 4096 * 2);
    unsigned short* Al = (unsigned short*)alloc((size_t)MB_TILES * 16 * 4096 * 2);
    // packed weights, reused per layer (max = W2)
    unsigned short* Wh = (unsigned short*)alloc((size_t)262144 * 2);
    unsigned short* Wl = (unsigned short*)alloc((size_t)262144 * 2);
    float* asb   = (float*)alloc((size_t)N_NODES * 8 * 4);
    float* adb   = (float*)alloc((size_t)N_NODES * 8 * 4);
    int*   offs  = (int*)alloc((N_NODES + 1) * 4);
    int*   deg   = (int*)alloc(N_NODES * 4);   // reused as scatter cursor
    int*   csrc  = (int*)alloc((size_t)N_EDGES_SL * 4);
    float* sums  = (float*)alloc(NGRAPH * 64 * 4);
    float* cnt   = (float*)alloc(NGRAPH * 4);
    float* bufX3 = (float*)Ah;  // conv3 agg output overlays Ah (dead after gemm3)

    hipMemsetAsync(deg, 0, N_NODES * 4, stream);
    hipMemsetAsync(sums, 0, NGRAPH * 64 * 4, stream);
    hipMemsetAsync(cnt, 0, NGRAPH * 4, stream);

    // CSR by dst (self-loops appended); deg doubles as cursor
    k_count<<<(N_EDGES + 255) / 256, 256, 0, stream>>>(ei, deg);
    k_scan<<<1, 256, 0, stream>>>(deg, offs, deg);
    k_scatter<<<(N_EDGES_SL + 255) / 256, 256, 0, stream>>>(ei, deg, csrc);

    // ---- conv1: K=256 (KB=8) ----
    k_packA<<<(MB_TILES * 8 * 512 + 255) / 256, 256, 0, stream>>>(x, Ah, Al, N_NODES, DIM_IN);
    k_packW<128><<<(4 * 8 * 128 * 4 + 255) / 256, 256, 0, stream>>>(W1, Wh, Wl, DIM_IN, F1);
    k_gemm8<8><<<dim3(MB_TILES, 4), 256, 0, stream>>>(Ah, Al, Wh, Wl, as1, ad1, Hf, asb, adb, N_NODES);
    k_agg8<<<7500, 256, 0, stream>>>(Hf, asb, adb, offs, csrc, b1, Ah, Al);

    // ---- conv2: K=512 (KB=16) ----
    k_packW<128><<<(4 * 16 * 128 * 4 + 255) / 256, 256, 0, stream>>>(W2, Wh, Wl, F1, F1);
    k_gemm8<16><<<dim3(MB_TILES, 4), 256, 0, stream>>>(Ah, Al, Wh, Wl, as2, ad2, Hf, asb, adb, N_NODES);
    k_agg8<<<7500, 256, 0, stream>>>(Hf, asb, adb, offs, csrc, b2, Ah, Al);

    // ---- conv3: K=512 (KB=16), Nn=64 (BN=64, NF=2) ----
    k_packW<64><<<(1 * 16 * 64 * 4 + 255) / 256, 256, 0, stream>>>(W3, Wh, Wl, F1, 64);
    k_gemm_mfma<16, 2><<<dim3(MB_TILES, 1), 256, 0, stream>>>(Ah, Al, Wh, Wl, bufH3, N_NODES, 64);
    k_alphas1<<<7500, 256, 0, stream>>>(bufH3, as3, ad3, asb, adb);
    k_agg1<<<7500, 256, 0, stream>>>(bufH3, asb, adb, offs, csrc, b3, bufX3);

    // ---- pool + fc ----
    k_pool<<<7500, 256, 0, stream>>>(bufX3, batch, sums, cnt);
    k_fc<<<NGRAPH, 128, 0, stream>>>(sums, cnt, Wfc, bfc, out);
}